// Round 8
// baseline (224.157 us; speedup 1.0000x reference)
//
#include <hip/hip_runtime.h>

// VectorQuantizer: B=32768, D=256, K=16
// out layout (all f32): [0, B*D) z_q ; [B*D] vq_loss ; [B*D+1, 2*B*D+1) indices (as float)

constexpr int Bn = 32768;
constexpr int Dn = 256;
constexpr int Kn = 16;
constexpr int NQUAD = Bn * Dn / 4;            // 2,097,152 quads
constexpr int GRID = 4096;
constexpr int BLOCK = 256;
constexpr int QPT = NQUAD / (GRID * BLOCK);   // exactly 2 quads/thread
constexpr int ROWP = 260;                     // padded cbt row: staging-write banks spread (2-way = free)
constexpr float LOSS_SCALE = 1.25f / (float)Bn;  // (1 + 0.25) * (1/B)

__global__ void vq_init_loss(float* out) {
    if (threadIdx.x == 0) out[(size_t)Bn * Dn] = 0.0f;
}

__global__ __launch_bounds__(BLOCK, 8) void vq_main(const float* __restrict__ z,
                                                    const float* __restrict__ cb,
                                                    float* __restrict__ out) {
    // codebook transposed into LDS: cbt[k*ROWP + d]
    __shared__ float cbt[Kn * ROWP];
    __shared__ float wsum[4];
    // vectorized staging: 4 iters x (float4 load + 4 strided ds_writes)
    // cb[i..i+3] share d = i>>4, k = (i&15)..+3 ; write banks (k*4+d) mod 32 spread
    #pragma unroll
    for (int it = 0; it < 4; ++it) {
        const int i4 = threadIdx.x + it * BLOCK;        // float4 index, 1024 total
        const float4 c4 = *reinterpret_cast<const float4*>(cb + i4 * 4);
        const int d  = i4 >> 2;
        const int k0 = (i4 & 3) * 4;
        cbt[(k0 + 0) * ROWP + d] = c4.x;
        cbt[(k0 + 1) * ROWP + d] = c4.y;
        cbt[(k0 + 2) * ROWP + d] = c4.z;
        cbt[(k0 + 3) * ROWP + d] = c4.w;
    }
    __syncthreads();

    float* __restrict__ zq   = out;
    float* __restrict__ idxf = out + (size_t)Bn * Dn + 1;

    const int tid = blockIdx.x * BLOCK + threadIdx.x;
    const int stride = GRID * BLOCK;
    const int d0 = (tid * 4) & (Dn - 1);   // same for both iterations (4*stride % 256 == 0)

    // two z-vectors in flight (+8 VGPR only)
    float4 zv0 = *reinterpret_cast<const float4*>(z + (size_t)tid * 4);
    float4 zv1 = *reinterpret_cast<const float4*>(z + (size_t)(tid + stride) * 4);

    float acc = 0.0f;
    #pragma unroll
    for (int it = 0; it < QPT; ++it) {
        const int f = (tid + it * stride) * 4;
        const float4 zv = (it == 0) ? zv0 : zv1;
        const float zz[4] = {zv.x, zv.y, zv.z, zv.w};

        float best[4] = {1e30f, 1e30f, 1e30f, 1e30f};
        float bc[4]   = {0.f, 0.f, 0.f, 0.f};
        int   bi[4]   = {0, 0, 0, 0};

        #pragma unroll
        for (int k = 0; k < Kn; ++k) {
            const float4 c = *reinterpret_cast<const float4*>(&cbt[k * ROWP + d0]);
            const float cc[4] = {c.x, c.y, c.z, c.w};
            #pragma unroll
            for (int j = 0; j < 4; ++j) {
                float dd = zz[j] - cc[j];
                float d2 = dd * dd;                 // exact same expr as reference -> identical rounding
                bool lt = d2 < best[j];             // strict <: first-min tie-break (jnp.argmin)
                best[j] = lt ? d2 : best[j];
                bc[j]   = lt ? cc[j] : bc[j];
                bi[j]   = lt ? k : bi[j];
            }
        }

        *reinterpret_cast<float4*>(zq + f) = make_float4(bc[0], bc[1], bc[2], bc[3]);

        // indices region starts at B*D+1 (4B-misaligned): scalar stores, L2 merges lines
        idxf[f + 0] = (float)bi[0];
        idxf[f + 1] = (float)bi[1];
        idxf[f + 2] = (float)bi[2];
        idxf[f + 3] = (float)bi[3];

        acc += best[0] + best[1] + best[2] + best[3];
    }

    // wave reduce (64 lanes)
    #pragma unroll
    for (int off = 32; off > 0; off >>= 1)
        acc += __shfl_down(acc, off, 64);

    const int lane = threadIdx.x & 63;
    const int wid  = threadIdx.x >> 6;
    if (lane == 0) wsum[wid] = acc;
    __syncthreads();
    if (threadIdx.x == 0) {
        float s = (wsum[0] + wsum[1] + wsum[2] + wsum[3]) * LOSS_SCALE;
        atomicAdd(out + (size_t)Bn * Dn, s);
    }
}

extern "C" void kernel_launch(void* const* d_in, const int* in_sizes, int n_in,
                              void* d_out, int out_size, void* d_ws, size_t ws_size,
                              hipStream_t stream) {
    const float* z  = (const float*)d_in[0];
    const float* cb = (const float*)d_in[1];
    float* out = (float*)d_out;

    vq_init_loss<<<1, 64, 0, stream>>>(out);
    vq_main<<<GRID, BLOCK, 0, stream>>>(z, cb, out);
}

// Round 9
// 138.648 us; speedup vs baseline: 1.6167x; 1.6167x over previous
//
#include <hip/hip_runtime.h>

// VectorQuantizer: B=32768, D=256, K=16
// out layout (all f32): [0, BD) z_q ; [BD] vq_loss ; [BD+1, 2BD+1) indices (as float)

constexpr int Bn = 32768;
constexpr int Dn = 256;
constexpr int Kn = 16;
constexpr int BD = Bn * Dn;                   // 8,388,608
constexpr int NQUAD = BD / 4;
constexpr int GRID = 4096;
constexpr int BLOCK = 256;
constexpr int QPT = NQUAD / (GRID * BLOCK);   // exactly 2 quads/thread
constexpr int ROWP = 260;                     // padded cbt row
constexpr float LOSS_SCALE = 1.25f / (float)Bn;  // (1 + 0.25) * (1/B)

__global__ void vq_init_loss(float* out) {
    if (threadIdx.x == 0) out[BD] = 0.0f;
}

__global__ __launch_bounds__(BLOCK, 8) void vq_main(const float* __restrict__ z,
                                                    const float* __restrict__ cb,
                                                    float* __restrict__ out) {
    __shared__ float cbt[Kn * ROWP];     // codebook transposed: cbt[k*ROWP + d]
    __shared__ float sidx[5 * BLOCK];    // idx staging, stride-5 packed (conflict-free)
    __shared__ float wsum[4];

    // vectorized staging: cb is (D,K) row-major; spread banks via ROWP=260
    #pragma unroll
    for (int it = 0; it < 4; ++it) {
        const int i4 = threadIdx.x + it * BLOCK;
        const float4 c4 = *reinterpret_cast<const float4*>(cb + i4 * 4);
        const int d  = i4 >> 2;
        const int k0 = (i4 & 3) * 4;
        cbt[(k0 + 0) * ROWP + d] = c4.x;
        cbt[(k0 + 1) * ROWP + d] = c4.y;
        cbt[(k0 + 2) * ROWP + d] = c4.z;
        cbt[(k0 + 3) * ROWP + d] = c4.w;
    }
    __syncthreads();

    const int lid = threadIdx.x;
    const int tid = blockIdx.x * BLOCK + lid;
    const int tstride = GRID * BLOCK;
    const int d0 = (tid * 4) & (Dn - 1);   // same both iterations (4*tstride % 256 == 0)

    // two z-vectors in flight
    float4 zv0 = *reinterpret_cast<const float4*>(z + (size_t)tid * 4);
    float4 zv1 = *reinterpret_cast<const float4*>(z + (size_t)(tid + tstride) * 4);

    float acc = 0.0f;
    #pragma unroll
    for (int it = 0; it < QPT; ++it) {
        const int F = (blockIdx.x * BLOCK + it * tstride) * 4;  // block-base element idx
        const int f = F + lid * 4;                              // this thread's element idx
        const float4 zv = (it == 0) ? zv0 : zv1;
        const float zz[4] = {zv.x, zv.y, zv.z, zv.w};

        float best[4] = {1e30f, 1e30f, 1e30f, 1e30f};
        float bc[4]   = {0.f, 0.f, 0.f, 0.f};
        int   bi[4]   = {0, 0, 0, 0};

        #pragma unroll
        for (int k = 0; k < Kn; ++k) {
            const float4 c = *reinterpret_cast<const float4*>(&cbt[k * ROWP + d0]);
            const float cc[4] = {c.x, c.y, c.z, c.w};
            #pragma unroll
            for (int j = 0; j < 4; ++j) {
                float dd = zz[j] - cc[j];
                float d2 = dd * dd;                 // identical expr to reference -> same rounding
                bool lt = d2 < best[j];             // strict <: first-min tie-break (jnp.argmin)
                best[j] = lt ? d2 : best[j];
                bc[j]   = lt ? cc[j] : bc[j];
                bi[j]   = lt ? k : bi[j];
            }
        }

        // z_q: aligned float4 store
        *reinterpret_cast<float4*>(out + f) = make_float4(bc[0], bc[1], bc[2], bc[3]);
        acc += best[0] + best[1] + best[2] + best[3];

        // ---- aligned index writes via LDS shift staging ----
        __syncthreads();                    // protect sidx reuse across iterations
        sidx[5 * lid + 0] = (float)bi[0];
        sidx[5 * lid + 1] = (float)bi[1];
        sidx[5 * lid + 2] = (float)bi[2];
        sidx[5 * lid + 3] = (float)bi[3];
        __syncthreads();

        // out position of element e is BD+1+e; aligned vecs cover {F+4l+3 .. F+4l+6}
        if (lid == 0) {                     // head: elements F, F+1, F+2
            out[BD + 1 + F + 0] = sidx[0];
            out[BD + 1 + F + 1] = sidx[1];
            out[BD + 1 + F + 2] = sidx[2];
        }
        if (lid < BLOCK - 1) {
            float4 v = make_float4(sidx[5 * lid + 3],
                                   sidx[5 * (lid + 1) + 0],
                                   sidx[5 * (lid + 1) + 1],
                                   sidx[5 * (lid + 1) + 2]);
            *reinterpret_cast<float4*>(out + BD + 4 + F + 4 * lid) = v;   // 16B-aligned
        } else {                            // tail: element F+1023
            out[BD + 1 + F + 1023] = sidx[5 * 255 + 3];
        }
    }

    // wave reduce (64 lanes)
    #pragma unroll
    for (int off = 32; off > 0; off >>= 1)
        acc += __shfl_down(acc, off, 64);

    const int lane = lid & 63;
    const int wid  = lid >> 6;
    if (lane == 0) wsum[wid] = acc;
    __syncthreads();
    if (lid == 0) {
        float s = (wsum[0] + wsum[1] + wsum[2] + wsum[3]) * LOSS_SCALE;
        atomicAdd(out + BD, s);
    }
}

extern "C" void kernel_launch(void* const* d_in, const int* in_sizes, int n_in,
                              void* d_out, int out_size, void* d_ws, size_t ws_size,
                              hipStream_t stream) {
    const float* z  = (const float*)d_in[0];
    const float* cb = (const float*)d_in[1];
    float* out = (float*)d_out;

    vq_init_loss<<<1, 64, 0, stream>>>(out);
    vq_main<<<GRID, BLOCK, 0, stream>>>(z, cb, out);
}

// Round 10
// 138.371 us; speedup vs baseline: 1.6200x; 1.0020x over previous
//
#include <hip/hip_runtime.h>

// VectorQuantizer: B=32768, D=256, K=16
// out layout (all f32): [0, BD) z_q ; [BD] vq_loss ; [BD+1, 2BD+1) indices (as float)

constexpr int Bn = 32768;
constexpr int Dn = 256;
constexpr int Kn = 16;
constexpr int BD = Bn * Dn;                   // 8,388,608
constexpr int NQUAD = BD / 4;
constexpr int GRID = 4096;
constexpr int BLOCK = 256;
constexpr int QPT = NQUAD / (GRID * BLOCK);   // exactly 2 quads/thread
constexpr int ROWP = 260;                     // padded cbt row (staging banks spread)
constexpr float LOSS_SCALE = 1.25f / (float)Bn;  // (1 + 0.25) * (1/B)

__global__ void vq_init_loss(float* out) {
    if (threadIdx.x == 0) out[BD] = 0.0f;
}

__global__ __launch_bounds__(BLOCK, 8) void vq_main(const float* __restrict__ z,
                                                    const float* __restrict__ cb,
                                                    float* __restrict__ out) {
    __shared__ float cbt[Kn * ROWP];     // codebook transposed: cbt[k*ROWP + d]
    __shared__ float wsum[4];

    // vectorized staging: cb is (D,K) row-major
    #pragma unroll
    for (int it = 0; it < 4; ++it) {
        const int i4 = threadIdx.x + it * BLOCK;
        const float4 c4 = *reinterpret_cast<const float4*>(cb + i4 * 4);
        const int d  = i4 >> 2;
        const int k0 = (i4 & 3) * 4;
        cbt[(k0 + 0) * ROWP + d] = c4.x;
        cbt[(k0 + 1) * ROWP + d] = c4.y;
        cbt[(k0 + 2) * ROWP + d] = c4.z;
        cbt[(k0 + 3) * ROWP + d] = c4.w;
    }
    __syncthreads();

    const int lid  = threadIdx.x;
    const int lane = lid & 63;
    const int tid  = blockIdx.x * BLOCK + lid;
    const int tstride = GRID * BLOCK;
    const int d0 = (tid * 4) & (Dn - 1);   // same both iterations (4*tstride % 256 == 0)

    // two z-vectors in flight (cheap MLP, stays ~32-36 VGPR)
    float4 zv0 = *reinterpret_cast<const float4*>(z + (size_t)tid * 4);
    float4 zv1 = *reinterpret_cast<const float4*>(z + (size_t)(tid + tstride) * 4);

    float acc = 0.0f;
    #pragma unroll
    for (int it = 0; it < QPT; ++it) {
        const int f = (tid + it * tstride) * 4;
        const float4 zv = (it == 0) ? zv0 : zv1;
        const float zz[4] = {zv.x, zv.y, zv.z, zv.w};

        float best[4] = {1e30f, 1e30f, 1e30f, 1e30f};
        float bc[4]   = {0.f, 0.f, 0.f, 0.f};
        int   bi[4]   = {0, 0, 0, 0};

        #pragma unroll
        for (int k = 0; k < Kn; ++k) {
            const float4 c = *reinterpret_cast<const float4*>(&cbt[k * ROWP + d0]);
            const float cc[4] = {c.x, c.y, c.z, c.w};
            #pragma unroll
            for (int j = 0; j < 4; ++j) {
                float dd = zz[j] - cc[j];
                float d2 = dd * dd;                 // identical expr to reference -> same rounding
                bool lt = d2 < best[j];             // strict <: first-min tie-break (jnp.argmin)
                best[j] = lt ? d2 : best[j];
                bc[j]   = lt ? cc[j] : bc[j];
                bi[j]   = lt ? k : bi[j];
            }
        }

        // z_q: aligned float4 store
        *reinterpret_cast<float4*>(out + f) = make_float4(bc[0], bc[1], bc[2], bc[3]);
        acc += best[0] + best[1] + best[2] + best[3];

        // ---- aligned index stores via wave-level shift (no barriers, no staging LDS) ----
        // element e lands at out[BD+1+e]; aligned quad BD+4+f covers elements {f+3, f+4, f+5, f+6}
        const float i0 = (float)bi[0], i1 = (float)bi[1], i2 = (float)bi[2], i3 = (float)bi[3];
        const float n0 = __shfl_down(i0, 1, 64);   // next thread's bi0..2 (garbage on lane 63, unused)
        const float n1 = __shfl_down(i1, 1, 64);
        const float n2 = __shfl_down(i2, 1, 64);
        if (lane == 0) {                            // head: own elements f, f+1, f+2
            out[BD + 1 + f + 0] = i0;
            out[BD + 1 + f + 1] = i1;
            out[BD + 1 + f + 2] = i2;
        }
        if (lane < 63) {
            *reinterpret_cast<float4*>(out + BD + 4 + f) = make_float4(i3, n0, n1, n2);
        } else {                                    // wave tail: own element f+3 only
            out[BD + 4 + f] = i3;                   // next wave's lane 0 covers f+4..6
        }
    }

    // wave reduce (64 lanes)
    #pragma unroll
    for (int off = 32; off > 0; off >>= 1)
        acc += __shfl_down(acc, off, 64);

    const int wid = lid >> 6;
    if (lane == 0) wsum[wid] = acc;
    __syncthreads();
    if (lid == 0) {
        float s = (wsum[0] + wsum[1] + wsum[2] + wsum[3]) * LOSS_SCALE;
        atomicAdd(out + BD, s);
    }
}

extern "C" void kernel_launch(void* const* d_in, const int* in_sizes, int n_in,
                              void* d_out, int out_size, void* d_ws, size_t ws_size,
                              hipStream_t stream) {
    const float* z  = (const float*)d_in[0];
    const float* cb = (const float*)d_in[1];
    float* out = (float*)d_out;

    vq_init_loss<<<1, 64, 0, stream>>>(out);
    vq_main<<<GRID, BLOCK, 0, stream>>>(z, cb, out);
}